// Round 1
// baseline (97.010 us; speedup 1.0000x reference)
//
#include <hip/hip_runtime.h>

// PatchManifold: bilinear 10x downsample (exact 4-pixel average), 16x16
// pairwise patch affinity mean(exp(-(Pa-Pb)^2)), zero 2 smallest per row.
//
// Input : d_in[0] = targets f32 [8,3,2560,2560]
// Output: d_out   = f32 [16,16]
// ws    : 8 shadow copies x 256 slots of f64 pair accumulators (16 KiB)

#define W_IN 2560
#define IMG_STRIDE (2560 * 2560)
#define NPAIR_SLOTS 256
#define NSHADOW 8
#define D_TOTAL 98304.0

__global__ __launch_bounds__(64) void pm_accum(const float* __restrict__ in,
                                               double* __restrict__ acc) {
    const int blk = blockIdx.x;      // 0..1535 = img(24) * hh(64)
    const int hh  = blk & 63;
    const int img = blk >> 6;        // b*3 + c
    const int ww  = threadIdx.x;     // 0..63

    const float* base = in + (size_t)img * IMG_STRIDE;

    // 16 patch values for this d = (img, hh, ww)
    float P[16];
#pragma unroll
    for (int n = 0; n < 4; ++n) {
        const int row0 = 10 * (n * 64 + hh) + 4;   // and row0+1
        const float* r0 = base + (size_t)row0 * W_IN;
#pragma unroll
        for (int m = 0; m < 4; ++m) {
            const int col = 10 * (m * 64 + ww) + 4;  // even -> 8B aligned float2
            float2 t = *reinterpret_cast<const float2*>(r0 + col);
            float2 u = *reinterpret_cast<const float2*>(r0 + W_IN + col);
            P[n * 4 + m] = 0.25f * ((t.x + t.y) + (u.x + u.y));
        }
    }

    double* shadow = acc + (size_t)(blk & (NSHADOW - 1)) * NPAIR_SLOTS;

    int k = 0;
#pragma unroll
    for (int a = 0; a < 16; ++a) {
#pragma unroll
        for (int b = a + 1; b < 16; ++b) {
            float d = P[a] - P[b];
            float v = __expf(-d * d);
            // full 64-lane butterfly: every lane ends with the wave sum
#pragma unroll
            for (int s = 32; s >= 1; s >>= 1) v += __shfl_xor(v, s, 64);
            if (ww == (k & 63)) atomicAdd(&shadow[a * 16 + b], (double)v);
            ++k;
        }
    }
}

__global__ __launch_bounds__(256) void pm_finish(const double* __restrict__ acc,
                                                 float* __restrict__ out) {
    __shared__ float aff[256];
    const int tid = threadIdx.x;     // 0..255
    const int a = tid >> 4, b = tid & 15;
    if (a < b) {
        double s = 0.0;
#pragma unroll
        for (int c = 0; c < NSHADOW; ++c) s += acc[c * NPAIR_SLOTS + tid];
        float v = (float)(s * (1.0 / D_TOTAL));
        aff[a * 16 + b] = v;
        aff[b * 16 + a] = v;
    } else if (a == b) {
        aff[tid] = 1.0f;             // exp(0) mean == 1 exactly
    }
    __syncthreads();
    if (tid < 16) {
        const float* row = &aff[tid * 16];
        // two smallest, stable first-index tie-break (matches jnp.argsort)
        float v1 = 1e30f; int i1 = -1;
        for (int j = 0; j < 16; ++j) {
            float x = row[j];
            if (x < v1) { v1 = x; i1 = j; }
        }
        float v2 = 1e30f; int i2 = -1;
        for (int j = 0; j < 16; ++j) {
            if (j == i1) continue;
            float x = row[j];
            if (x < v2) { v2 = x; i2 = j; }
        }
        for (int j = 0; j < 16; ++j)
            out[tid * 16 + j] = (j == i1 || j == i2) ? 0.0f : row[j];
    }
}

extern "C" void kernel_launch(void* const* d_in, const int* in_sizes, int n_in,
                              void* d_out, int out_size, void* d_ws, size_t ws_size,
                              hipStream_t stream) {
    const float* in = (const float*)d_in[0];
    float* out = (float*)d_out;
    double* acc = (double*)d_ws;

    hipMemsetAsync(d_ws, 0, NSHADOW * NPAIR_SLOTS * sizeof(double), stream);
    pm_accum<<<dim3(1536), dim3(64), 0, stream>>>(in, acc);
    pm_finish<<<dim3(1), dim3(256), 0, stream>>>(acc, out);
}

// Round 2
// 39.921 us; speedup vs baseline: 2.4300x; 2.4300x over previous
//
#include <hip/hip_runtime.h>

// PatchManifold: bilinear 10x downsample (exact 4-pixel average, frac==0.5),
// 16x16 pairwise patch affinity mean(exp(-(Pa-Pb)^2)), zero 2 smallest/row.
//
// Input : d_in[0] = targets f32 [8,3,2560,2560]
// Output: d_out   = f32 [16,16]
//
// Fast path (needs ~6.4 MB ws):
//   K1: resize -> P_mat [16][98304] f32 in ws (massively parallel strided read)
//   K2: 120 exps/thread + transposed 126-shfl butterfly + LDS combine +
//       f64 atomics into 32 shadow accumulators
//   K3: finish (mean, mirror, diag=1, zero 2 smallest per row)
// Fallback path (16 KB ws): round-1 fused version.

#define W_IN 2560
#define IMG_STRIDE (2560 * 2560)
#define D_TOTAL_I 98304
#define D_TOTAL 98304.0

// ---- fast-path layout in ws ----
#define NSHADOW_F 32
#define SLOT_STRIDE 128            // 120 pairs padded
#define SHADOW_BYTES (NSHADOW_F * SLOT_STRIDE * 8)   // 32 KB
#define PMAT_OFF 65536             // bytes; P_mat after shadow region
#define WS_NEEDED (PMAT_OFF + 16 * D_TOTAL_I * 4)

// ============================ fast path ============================

__global__ __launch_bounds__(256) void pm_resize(const float* __restrict__ in,
                                                 float* __restrict__ Pm) {
    const int blk = blockIdx.x;            // img*256 + hh*4 + n   (6144 blocks)
    const int n   = blk & 3;
    const int hh  = (blk >> 2) & 63;
    const int img = blk >> 8;
    const int m   = threadIdx.x >> 6;
    const int ww  = threadIdx.x & 63;

    const float* r0 = in + (size_t)img * IMG_STRIDE
                         + (size_t)(640 * n + 10 * hh + 4) * W_IN
                         + (640 * m + 10 * ww + 4);
    float2 t = *reinterpret_cast<const float2*>(r0);
    float2 u = *reinterpret_cast<const float2*>(r0 + W_IN);
    Pm[(size_t)(n * 4 + m) * D_TOTAL_I + img * 4096 + hh * 64 + ww] =
        0.25f * ((t.x + t.y) + (u.x + u.y));
}

__global__ __launch_bounds__(256) void pm_pairs(const float* __restrict__ Pm,
                                                double* __restrict__ acc) {
    const int tid  = threadIdx.x;
    const int lane = tid & 63;
    const int d    = blockIdx.x * 256 + tid;   // 384 blocks -> all 98304 d

    float P[16];
#pragma unroll
    for (int p = 0; p < 16; ++p) P[p] = Pm[p * D_TOTAL_I + d];

    float v[128];
    {
        int k = 0;
#pragma unroll
        for (int a = 0; a < 16; ++a)
#pragma unroll
            for (int b = a + 1; b < 16; ++b) {
                float df = P[a] - P[b];
                v[k++] = __expf(-df * df);
            }
#pragma unroll
        for (int i = 120; i < 128; ++i) v[i] = 0.0f;
    }

    // Transposed segmented butterfly: 6 stages, values/lane 128->2.
    // After stage sequence, lane holds slots i + 2*bitrev6(lane), i in {0,1},
    // each fully summed over the 64 lanes.
#define PM_STAGE(K, H)                                         \
    {                                                          \
        const bool bit = (lane >> (K)) & 1;                    \
        _Pragma("unroll")                                      \
        for (int i = 0; i < (H); ++i) {                        \
            float keep = bit ? v[i + (H)] : v[i];              \
            float send = bit ? v[i] : v[i + (H)];              \
            v[i] = keep + __shfl_xor(send, 1 << (K), 64);      \
        }                                                      \
    }
    PM_STAGE(0, 64)
    PM_STAGE(1, 32)
    PM_STAGE(2, 16)
    PM_STAGE(3, 8)
    PM_STAGE(4, 4)
    PM_STAGE(5, 2)
#undef PM_STAGE

    __shared__ float part[SLOT_STRIDE];
    if (tid < SLOT_STRIDE) part[tid] = 0.0f;
    __syncthreads();

    const int r = __brev(lane) >> 26;          // 6-bit bit-reverse
#pragma unroll
    for (int i = 0; i < 2; ++i) {
        int slot = i + 2 * r;
        if (slot < 120) atomicAdd(&part[slot], v[i]);
    }
    __syncthreads();

    if (tid < 120) {
        double* shadow = acc + (size_t)(blockIdx.x & (NSHADOW_F - 1)) * SLOT_STRIDE;
        atomicAdd(&shadow[tid], (double)part[tid]);
    }
}

__global__ __launch_bounds__(256) void pm_finish_fast(const double* __restrict__ acc,
                                                      float* __restrict__ out) {
    __shared__ float aff[256];
    const int tid = threadIdx.x;
    const int a = tid >> 4, b = tid & 15;
    if (a < b) {
        // pair index in the (a, b>a) nested-loop order
        int pp = 15 * a - (a * (a - 1)) / 2 + (b - a - 1);
        double s = 0.0;
#pragma unroll
        for (int c = 0; c < NSHADOW_F; ++c) s += acc[c * SLOT_STRIDE + pp];
        float vv = (float)(s * (1.0 / D_TOTAL));
        aff[a * 16 + b] = vv;
        aff[b * 16 + a] = vv;
    } else if (a == b) {
        aff[tid] = 1.0f;
    }
    __syncthreads();
    if (tid < 16) {
        const float* row = &aff[tid * 16];
        float v1 = 1e30f; int i1 = -1;
        for (int j = 0; j < 16; ++j) {
            float x = row[j];
            if (x < v1) { v1 = x; i1 = j; }
        }
        float v2 = 1e30f; int i2 = -1;
        for (int j = 0; j < 16; ++j) {
            if (j == i1) continue;
            float x = row[j];
            if (x < v2) { v2 = x; i2 = j; }
        }
        for (int j = 0; j < 16; ++j)
            out[tid * 16 + j] = (j == i1 || j == i2) ? 0.0f : row[j];
    }
}

// ============================ fallback path (round-1, verified) ============================

#define NPAIR_SLOTS 256
#define NSHADOW 8

__global__ __launch_bounds__(64) void pm_accum(const float* __restrict__ in,
                                               double* __restrict__ acc) {
    const int blk = blockIdx.x;
    const int hh  = blk & 63;
    const int img = blk >> 6;
    const int ww  = threadIdx.x;

    const float* base = in + (size_t)img * IMG_STRIDE;
    float P[16];
#pragma unroll
    for (int n = 0; n < 4; ++n) {
        const int row0 = 10 * (n * 64 + hh) + 4;
        const float* r0 = base + (size_t)row0 * W_IN;
#pragma unroll
        for (int m = 0; m < 4; ++m) {
            const int col = 10 * (m * 64 + ww) + 4;
            float2 t = *reinterpret_cast<const float2*>(r0 + col);
            float2 u = *reinterpret_cast<const float2*>(r0 + W_IN + col);
            P[n * 4 + m] = 0.25f * ((t.x + t.y) + (u.x + u.y));
        }
    }
    double* shadow = acc + (size_t)(blk & (NSHADOW - 1)) * NPAIR_SLOTS;
    int k = 0;
#pragma unroll
    for (int a = 0; a < 16; ++a)
#pragma unroll
        for (int b = a + 1; b < 16; ++b) {
            float dd = P[a] - P[b];
            float vv = __expf(-dd * dd);
#pragma unroll
            for (int s = 32; s >= 1; s >>= 1) vv += __shfl_xor(vv, s, 64);
            if (ww == (k & 63)) atomicAdd(&shadow[a * 16 + b], (double)vv);
            ++k;
        }
}

__global__ __launch_bounds__(256) void pm_finish(const double* __restrict__ acc,
                                                 float* __restrict__ out) {
    __shared__ float aff[256];
    const int tid = threadIdx.x;
    const int a = tid >> 4, b = tid & 15;
    if (a < b) {
        double s = 0.0;
#pragma unroll
        for (int c = 0; c < NSHADOW; ++c) s += acc[c * NPAIR_SLOTS + tid];
        float vv = (float)(s * (1.0 / D_TOTAL));
        aff[a * 16 + b] = vv;
        aff[b * 16 + a] = vv;
    } else if (a == b) {
        aff[tid] = 1.0f;
    }
    __syncthreads();
    if (tid < 16) {
        const float* row = &aff[tid * 16];
        float v1 = 1e30f; int i1 = -1;
        for (int j = 0; j < 16; ++j) {
            float x = row[j];
            if (x < v1) { v1 = x; i1 = j; }
        }
        float v2 = 1e30f; int i2 = -1;
        for (int j = 0; j < 16; ++j) {
            if (j == i1) continue;
            float x = row[j];
            if (x < v2) { v2 = x; i2 = j; }
        }
        for (int j = 0; j < 16; ++j)
            out[tid * 16 + j] = (j == i1 || j == i2) ? 0.0f : row[j];
    }
}

// ============================ launch ============================

extern "C" void kernel_launch(void* const* d_in, const int* in_sizes, int n_in,
                              void* d_out, int out_size, void* d_ws, size_t ws_size,
                              hipStream_t stream) {
    const float* in = (const float*)d_in[0];
    float* out = (float*)d_out;

    if (ws_size >= (size_t)WS_NEEDED) {
        double* acc = (double*)d_ws;
        float* Pm = (float*)((char*)d_ws + PMAT_OFF);
        hipMemsetAsync(d_ws, 0, SHADOW_BYTES, stream);
        pm_resize<<<dim3(6144), dim3(256), 0, stream>>>(in, Pm);
        pm_pairs<<<dim3(384), dim3(256), 0, stream>>>(Pm, acc);
        pm_finish_fast<<<dim3(1), dim3(256), 0, stream>>>(acc, out);
    } else {
        double* acc = (double*)d_ws;
        hipMemsetAsync(d_ws, 0, NSHADOW * NPAIR_SLOTS * sizeof(double), stream);
        pm_accum<<<dim3(1536), dim3(64), 0, stream>>>(in, acc);
        pm_finish<<<dim3(1), dim3(256), 0, stream>>>(acc, out);
    }
}